// Round 1
// baseline (257.578 us; speedup 1.0000x reference)
//
#include <hip/hip_runtime.h>
#include <math.h>

#define NPIX 4096        // N = H*W = 64*64
#define CCH 8            // channels
#define ROWS 64          // rows per block
#define BLK 64           // one wave per block
#define L2E 1.44269504088896340736f

__global__ __launch_bounds__(BLK) void attn_fused(
    const float* __restrict__ x,
    const float* __restrict__ Wq, const float* __restrict__ bq,
    const float* __restrict__ Wk, const float* __restrict__ bk,
    const float* __restrict__ Wv, const float* __restrict__ bv,
    const float* __restrict__ gamma_p,
    float* __restrict__ y, float* __restrict__ attn)
{
    __shared__ float ks[NPIX];
    __shared__ float vs[NPIX];
    __shared__ float qrow[ROWS];
    __shared__ float crow[ROWS];

    const int b = blockIdx.y;
    const int rowbase = blockIdx.x * ROWS;
    const int tid = threadIdx.x;

    // Weights: uniform across lanes -> scalar loads. Fully unrolled (static idx).
    float wq[CCH], wk[CCH], wv[CCH];
#pragma unroll
    for (int c = 0; c < CCH; ++c) { wq[c] = Wq[c]; wk[c] = Wk[c]; wv[c] = Wv[c]; }
    const float bqv = bq[0], bkv = bk[0], bvv = bv[0];
    const float gamma = gamma_p[0];

    const float* xb = x + (size_t)b * NPIX * CCH;

    // ---- stage k, v into LDS (recomputed per block; x tile comes from L2/L3) ----
    for (int j = tid; j < NPIX; j += BLK) {
        const float4* xp = reinterpret_cast<const float4*>(xb + (size_t)j * CCH);
        float4 x0 = xp[0];
        float4 x1 = xp[1];
        float kj = bkv;
        kj = fmaf(x0.x, wk[0], kj); kj = fmaf(x0.y, wk[1], kj);
        kj = fmaf(x0.z, wk[2], kj); kj = fmaf(x0.w, wk[3], kj);
        kj = fmaf(x1.x, wk[4], kj); kj = fmaf(x1.y, wk[5], kj);
        kj = fmaf(x1.z, wk[6], kj); kj = fmaf(x1.w, wk[7], kj);
        float vj = bvv;
        vj = fmaf(x0.x, wv[0], vj); vj = fmaf(x0.y, wv[1], vj);
        vj = fmaf(x0.z, wv[2], vj); vj = fmaf(x0.w, wv[3], vj);
        vj = fmaf(x1.x, wv[4], vj); vj = fmaf(x1.y, wv[5], vj);
        vj = fmaf(x1.z, wv[6], vj); vj = fmaf(x1.w, wv[7], vj);
        ks[j] = kj;
        vs[j] = vj;
    }
    __syncthreads();

    // ---- kmax / kmin over the batch's k vector (single-wave butterfly) ----
    float kmx = -INFINITY, kmn = INFINITY;
    for (int j = tid; j < NPIX; j += BLK) {
        float kj = ks[j];
        kmx = fmaxf(kmx, kj);
        kmn = fminf(kmn, kj);
    }
#pragma unroll
    for (int off = 32; off > 0; off >>= 1) {
        kmx = fmaxf(kmx, __shfl_xor(kmx, off));
        kmn = fminf(kmn, __shfl_xor(kmn, off));
    }

    // ---- per-thread row: q_i, analytic row max, online sum + PV reduction ----
    const int i = rowbase + tid;
    const float4* xq = reinterpret_cast<const float4*>(xb + (size_t)i * CCH);
    float4 a0 = xq[0];
    float4 a1 = xq[1];
    float q = bqv;
    q = fmaf(a0.x, wq[0], q); q = fmaf(a0.y, wq[1], q);
    q = fmaf(a0.z, wq[2], q); q = fmaf(a0.w, wq[3], q);
    q = fmaf(a1.x, wq[4], q); q = fmaf(a1.y, wq[5], q);
    q = fmaf(a1.z, wq[6], q); q = fmaf(a1.w, wq[7], q);

    const float q2 = q * L2E;                       // base-2 domain
    const float m2 = q2 * ((q >= 0.f) ? kmx : kmn); // = max_j q2*k_j  (exact row max)

    float s0 = 0.f, s1 = 0.f, s2 = 0.f, s3 = 0.f;
    float o0 = 0.f, o1 = 0.f, o2 = 0.f, o3 = 0.f;
    for (int j = 0; j < NPIX; j += 4) {
        float4 kk = *reinterpret_cast<const float4*>(&ks[j]); // broadcast read
        float4 vv = *reinterpret_cast<const float4*>(&vs[j]);
        float e0 = exp2f(fmaf(q2, kk.x, -m2));
        float e1 = exp2f(fmaf(q2, kk.y, -m2));
        float e2 = exp2f(fmaf(q2, kk.z, -m2));
        float e3 = exp2f(fmaf(q2, kk.w, -m2));
        s0 += e0; s1 += e1; s2 += e2; s3 += e3;
        o0 = fmaf(e0, vv.x, o0);
        o1 = fmaf(e1, vv.y, o1);
        o2 = fmaf(e2, vv.z, o2);
        o3 = fmaf(e3, vv.w, o3);
    }
    const float s = (s0 + s1) + (s2 + s3);
    const float o = (o0 + o1) + (o2 + o3);
    const float outv = o / s;

    // ---- y = out*gamma + x  (d==1 broadcasts over C) ----
    const float og = outv * gamma;
    float* yp = y + ((size_t)b * NPIX + i) * CCH;
    float4 y0 = { og + a0.x, og + a0.y, og + a0.z, og + a0.w };
    float4 y1 = { og + a1.x, og + a1.y, og + a1.z, og + a1.w };
    *reinterpret_cast<float4*>(yp) = y0;
    *reinterpret_cast<float4*>(yp + 4) = y1;

    // row constants for the write phase: attn = exp2(q2*k_j - (m2 + log2(s)))
    qrow[tid] = q2;
    crow[tid] = m2 + log2f(s);
    __syncthreads();

    // ---- stream the attention tile: 64 rows x 4096 cols, coalesced float4 ----
    float* ap0 = attn + ((size_t)b * NPIX + rowbase) * (size_t)NPIX;
    for (int r = 0; r < ROWS; ++r) {
        const float qr = qrow[r];
        const float cr = crow[r];
        float* ap = ap0 + (size_t)r * NPIX;
#pragma unroll 4
        for (int j4 = tid * 4; j4 < NPIX; j4 += BLK * 4) {
            float4 kk = *reinterpret_cast<const float4*>(&ks[j4]);
            float4 e;
            e.x = exp2f(fmaf(qr, kk.x, -cr));
            e.y = exp2f(fmaf(qr, kk.y, -cr));
            e.z = exp2f(fmaf(qr, kk.z, -cr));
            e.w = exp2f(fmaf(qr, kk.w, -cr));
            *reinterpret_cast<float4*>(&ap[j4]) = e;
        }
    }
}

extern "C" void kernel_launch(void* const* d_in, const int* in_sizes, int n_in,
                              void* d_out, int out_size, void* d_ws, size_t ws_size,
                              hipStream_t stream) {
    const float* x   = (const float*)d_in[0];
    const float* Wq  = (const float*)d_in[1];
    const float* bq  = (const float*)d_in[2];
    const float* Wk  = (const float*)d_in[3];
    const float* bk  = (const float*)d_in[4];
    const float* Wv  = (const float*)d_in[5];
    const float* bv  = (const float*)d_in[6];
    const float* gm  = (const float*)d_in[7];

    const int B = in_sizes[0] / (NPIX * CCH);   // = 8
    float* y    = (float*)d_out;
    float* attn = y + (size_t)B * NPIX * CCH;   // attention follows y, flat

    dim3 grid(NPIX / ROWS, B);
    attn_fused<<<grid, BLK, 0, stream>>>(x, Wq, bq, Wk, bk, Wv, bv, gm, y, attn);
}

// Round 3
// 136.237 us; speedup vs baseline: 1.8907x; 1.8907x over previous
//
#include <hip/hip_runtime.h>
#include <math.h>

#define NPIX 4096        // N = H*W = 64*64
#define CCH 8            // channels
#define ROWS 64          // rows per block (output tile)
#define BLK 256          // 4 waves per block
#define NW   (BLK/64)
#define L2E 1.44269504088896340736f

typedef float floatx4 __attribute__((ext_vector_type(4)));

__global__ __launch_bounds__(BLK) void attn_fused(
    const float* __restrict__ x,
    const float* __restrict__ Wq, const float* __restrict__ bq,
    const float* __restrict__ Wk, const float* __restrict__ bk,
    const float* __restrict__ Wv, const float* __restrict__ bv,
    const float* __restrict__ gamma_p,
    float* __restrict__ y, float* __restrict__ attn)
{
    __shared__ float ks[NPIX];
    __shared__ float vs[NPIX];
    __shared__ float qrow[ROWS];
    __shared__ float crow[ROWS];
    __shared__ float spart[NW][ROWS];
    __shared__ float opart[NW][ROWS];
    __shared__ float kred[2][NW];

    const int b = blockIdx.y;
    const int rowbase = blockIdx.x * ROWS;
    const int tid = threadIdx.x;
    const int wid = tid >> 6;
    const int lane = tid & 63;

    // Weights: uniform across lanes -> scalar loads.
    float wq[CCH], wk[CCH], wv[CCH];
#pragma unroll
    for (int c = 0; c < CCH; ++c) { wq[c] = Wq[c]; wk[c] = Wk[c]; wv[c] = Wv[c]; }
    const float bqv = bq[0], bkv = bk[0], bvv = bv[0];
    const float gamma = gamma_p[0];

    const float* xb = x + (size_t)b * NPIX * CCH;

    // ---- stage k, v into LDS; track k min/max on the fly ----
    float kmx = -INFINITY, kmn = INFINITY;
    for (int j = tid; j < NPIX; j += BLK) {
        const float4* xp = reinterpret_cast<const float4*>(xb + (size_t)j * CCH);
        float4 x0 = xp[0];
        float4 x1 = xp[1];
        float kj = bkv;
        kj = fmaf(x0.x, wk[0], kj); kj = fmaf(x0.y, wk[1], kj);
        kj = fmaf(x0.z, wk[2], kj); kj = fmaf(x0.w, wk[3], kj);
        kj = fmaf(x1.x, wk[4], kj); kj = fmaf(x1.y, wk[5], kj);
        kj = fmaf(x1.z, wk[6], kj); kj = fmaf(x1.w, wk[7], kj);
        float vj = bvv;
        vj = fmaf(x0.x, wv[0], vj); vj = fmaf(x0.y, wv[1], vj);
        vj = fmaf(x0.z, wv[2], vj); vj = fmaf(x0.w, wv[3], vj);
        vj = fmaf(x1.x, wv[4], vj); vj = fmaf(x1.y, wv[5], vj);
        vj = fmaf(x1.z, wv[6], vj); vj = fmaf(x1.w, wv[7], vj);
        ks[j] = kj;
        vs[j] = vj;
        kmx = fmaxf(kmx, kj);
        kmn = fminf(kmn, kj);
    }
#pragma unroll
    for (int off = 32; off > 0; off >>= 1) {
        kmx = fmaxf(kmx, __shfl_xor(kmx, off));
        kmn = fminf(kmn, __shfl_xor(kmn, off));
    }
    if (lane == 0) { kred[0][wid] = kmx; kred[1][wid] = kmn; }
    __syncthreads();
    kmx = fmaxf(fmaxf(kred[0][0], kred[0][1]), fmaxf(kred[0][2], kred[0][3]));
    kmn = fminf(fminf(kred[1][0], kred[1][1]), fminf(kred[1][2], kred[1][3]));

    // ---- row phase: 4 threads per row, each sums a 1024-wide quarter ----
    const int r = lane;                  // row within tile (0..63)
    const int i = rowbase + r;
    const float4* xq = reinterpret_cast<const float4*>(xb + (size_t)i * CCH);
    float4 a0 = xq[0];
    float4 a1 = xq[1];
    float q = bqv;
    q = fmaf(a0.x, wq[0], q); q = fmaf(a0.y, wq[1], q);
    q = fmaf(a0.z, wq[2], q); q = fmaf(a0.w, wq[3], q);
    q = fmaf(a1.x, wq[4], q); q = fmaf(a1.y, wq[5], q);
    q = fmaf(a1.z, wq[6], q); q = fmaf(a1.w, wq[7], q);

    const float q2 = q * L2E;                       // base-2 domain
    const float m2 = q2 * ((q >= 0.f) ? kmx : kmn); // exact row max of q2*k_j

    float s0 = 0.f, s1 = 0.f, s2 = 0.f, s3 = 0.f;
    float o0 = 0.f, o1 = 0.f, o2 = 0.f, o3 = 0.f;
    const int j0 = wid * (NPIX / NW);
    for (int j = j0; j < j0 + NPIX / NW; j += 4) {
        float4 kk = *reinterpret_cast<const float4*>(&ks[j]); // broadcast read
        float4 vv = *reinterpret_cast<const float4*>(&vs[j]);
        float e0 = exp2f(fmaf(q2, kk.x, -m2));
        float e1 = exp2f(fmaf(q2, kk.y, -m2));
        float e2 = exp2f(fmaf(q2, kk.z, -m2));
        float e3 = exp2f(fmaf(q2, kk.w, -m2));
        s0 += e0; s1 += e1; s2 += e2; s3 += e3;
        o0 = fmaf(e0, vv.x, o0);
        o1 = fmaf(e1, vv.y, o1);
        o2 = fmaf(e2, vv.z, o2);
        o3 = fmaf(e3, vv.w, o3);
    }
    spart[wid][r] = (s0 + s1) + (s2 + s3);
    opart[wid][r] = (o0 + o1) + (o2 + o3);
    __syncthreads();

    if (tid < ROWS) {
        const float s = (spart[0][tid] + spart[1][tid]) + (spart[2][tid] + spart[3][tid]);
        const float o = (opart[0][tid] + opart[1][tid]) + (opart[2][tid] + opart[3][tid]);
        const float outv = o / s;
        // y = out*gamma + x  (d==1 broadcasts over C)
        const float og = outv * gamma;
        const int i2 = rowbase + tid;
        const float4* xr = reinterpret_cast<const float4*>(xb + (size_t)i2 * CCH);
        float4 b0 = xr[0];
        float4 b1 = xr[1];
        float* yp = y + ((size_t)b * NPIX + i2) * CCH;
        float4 y0 = { og + b0.x, og + b0.y, og + b0.z, og + b0.w };
        float4 y1 = { og + b1.x, og + b1.y, og + b1.z, og + b1.w };
        *reinterpret_cast<float4*>(yp) = y0;
        *reinterpret_cast<float4*>(yp + 4) = y1;
        qrow[tid] = q2;
        crow[tid] = m2 + log2f(s);
    }
    __syncthreads();

    // ---- stream the attention tile: 64 rows x 4096 cols, coalesced float4 ----
    float* ap0 = attn + ((size_t)b * NPIX + rowbase) * (size_t)NPIX;
    for (int rr = 0; rr < ROWS; ++rr) {
        const float qr = qrow[rr];
        const float cr = crow[rr];
        float* ap = ap0 + (size_t)rr * NPIX;
#pragma unroll
        for (int j4 = tid * 4; j4 < NPIX; j4 += BLK * 4) {
            float4 kk = *reinterpret_cast<const float4*>(&ks[j4]);
            floatx4 e;
            e.x = exp2f(fmaf(qr, kk.x, -cr));
            e.y = exp2f(fmaf(qr, kk.y, -cr));
            e.z = exp2f(fmaf(qr, kk.z, -cr));
            e.w = exp2f(fmaf(qr, kk.w, -cr));
            __builtin_nontemporal_store(e, reinterpret_cast<floatx4*>(&ap[j4]));
        }
    }
}

extern "C" void kernel_launch(void* const* d_in, const int* in_sizes, int n_in,
                              void* d_out, int out_size, void* d_ws, size_t ws_size,
                              hipStream_t stream) {
    const float* x   = (const float*)d_in[0];
    const float* Wq  = (const float*)d_in[1];
    const float* bq  = (const float*)d_in[2];
    const float* Wk  = (const float*)d_in[3];
    const float* bk  = (const float*)d_in[4];
    const float* Wv  = (const float*)d_in[5];
    const float* bv  = (const float*)d_in[6];
    const float* gm  = (const float*)d_in[7];

    const int B = in_sizes[0] / (NPIX * CCH);   // = 8
    float* y    = (float*)d_out;
    float* attn = y + (size_t)B * NPIX * CCH;   // attention follows y, flat

    dim3 grid(NPIX / ROWS, B);
    attn_fused<<<grid, BLK, 0, stream>>>(x, Wq, bq, Wk, bk, Wv, bv, gm, y, attn);
}

// Round 4
// 122.067 us; speedup vs baseline: 2.1101x; 1.1161x over previous
//
#include <hip/hip_runtime.h>
#include <math.h>

#define NPIX 4096        // N = H*W = 64*64
#define CCH 8            // channels
#define ROWS 32          // rows per block (output tile)
#define BLK 256          // 4 waves per block
#define NW   (BLK/64)
#define NP   (BLK/ROWS)  // 8 partial-sum threads per row
#define SEG  (NPIX/NP)   // 512 columns per partial
#define L2E 1.44269504088896340736f

typedef float floatx4 __attribute__((ext_vector_type(4)));

__global__ __launch_bounds__(BLK) void attn_fused(
    const float* __restrict__ x,
    const float* __restrict__ Wq, const float* __restrict__ bq,
    const float* __restrict__ Wk, const float* __restrict__ bk,
    const float* __restrict__ Wv, const float* __restrict__ bv,
    const float* __restrict__ gamma_p,
    float* __restrict__ y, float* __restrict__ attn)
{
    __shared__ float ks[NPIX];
    __shared__ float vs[NPIX];
    __shared__ float qrow[ROWS];
    __shared__ float crow[ROWS];
    __shared__ float spart[NP][ROWS];
    __shared__ float opart[NP][ROWS];
    __shared__ float kred[2][NW];

    const int b = blockIdx.y;
    const int rowbase = blockIdx.x * ROWS;
    const int tid = threadIdx.x;
    const int wid = tid >> 6;
    const int lane = tid & 63;

    // Weights: uniform across lanes -> scalar loads.
    float wq[CCH], wk[CCH], wv[CCH];
#pragma unroll
    for (int c = 0; c < CCH; ++c) { wq[c] = Wq[c]; wk[c] = Wk[c]; wv[c] = Wv[c]; }
    const float bqv = bq[0], bkv = bk[0], bvv = bv[0];
    const float gamma = gamma_p[0];

    const float* xb = x + (size_t)b * NPIX * CCH;

    // ---- stage k, v into LDS; track k min/max on the fly ----
    float kmx = -INFINITY, kmn = INFINITY;
    for (int j = tid; j < NPIX; j += BLK) {
        const float4* xp = reinterpret_cast<const float4*>(xb + (size_t)j * CCH);
        float4 x0 = xp[0];
        float4 x1 = xp[1];
        float kj = bkv;
        kj = fmaf(x0.x, wk[0], kj); kj = fmaf(x0.y, wk[1], kj);
        kj = fmaf(x0.z, wk[2], kj); kj = fmaf(x0.w, wk[3], kj);
        kj = fmaf(x1.x, wk[4], kj); kj = fmaf(x1.y, wk[5], kj);
        kj = fmaf(x1.z, wk[6], kj); kj = fmaf(x1.w, wk[7], kj);
        float vj = bvv;
        vj = fmaf(x0.x, wv[0], vj); vj = fmaf(x0.y, wv[1], vj);
        vj = fmaf(x0.z, wv[2], vj); vj = fmaf(x0.w, wv[3], vj);
        vj = fmaf(x1.x, wv[4], vj); vj = fmaf(x1.y, wv[5], vj);
        vj = fmaf(x1.z, wv[6], vj); vj = fmaf(x1.w, wv[7], vj);
        ks[j] = kj;
        vs[j] = vj;
        kmx = fmaxf(kmx, kj);
        kmn = fminf(kmn, kj);
    }
#pragma unroll
    for (int off = 32; off > 0; off >>= 1) {
        kmx = fmaxf(kmx, __shfl_xor(kmx, off));
        kmn = fminf(kmn, __shfl_xor(kmn, off));
    }
    if (lane == 0) { kred[0][wid] = kmx; kred[1][wid] = kmn; }
    __syncthreads();
    kmx = fmaxf(fmaxf(kred[0][0], kred[0][1]), fmaxf(kred[0][2], kred[0][3]));
    kmn = fminf(fminf(kred[1][0], kred[1][1]), fminf(kred[1][2], kred[1][3]));

    // ---- row phase: NP threads per row, each sums a SEG-wide stripe ----
    const int r = tid & (ROWS - 1);      // row within tile
    const int p = tid >> 5;              // stripe index (0..NP-1)
    const int i = rowbase + r;
    const float4* xq = reinterpret_cast<const float4*>(xb + (size_t)i * CCH);
    float4 a0 = xq[0];
    float4 a1 = xq[1];
    float q = bqv;
    q = fmaf(a0.x, wq[0], q); q = fmaf(a0.y, wq[1], q);
    q = fmaf(a0.z, wq[2], q); q = fmaf(a0.w, wq[3], q);
    q = fmaf(a1.x, wq[4], q); q = fmaf(a1.y, wq[5], q);
    q = fmaf(a1.z, wq[6], q); q = fmaf(a1.w, wq[7], q);

    const float q2 = q * L2E;                       // base-2 domain
    const float m2 = q2 * ((q >= 0.f) ? kmx : kmn); // exact row max of q2*k_j

    float s0 = 0.f, s1 = 0.f, s2 = 0.f, s3 = 0.f;
    float o0 = 0.f, o1 = 0.f, o2 = 0.f, o3 = 0.f;
    const int j0 = p * SEG;
    for (int j = j0; j < j0 + SEG; j += 4) {
        float4 kk = *reinterpret_cast<const float4*>(&ks[j]);
        float4 vv = *reinterpret_cast<const float4*>(&vs[j]);
        float e0 = exp2f(fmaf(q2, kk.x, -m2));
        float e1 = exp2f(fmaf(q2, kk.y, -m2));
        float e2 = exp2f(fmaf(q2, kk.z, -m2));
        float e3 = exp2f(fmaf(q2, kk.w, -m2));
        s0 += e0; s1 += e1; s2 += e2; s3 += e3;
        o0 = fmaf(e0, vv.x, o0);
        o1 = fmaf(e1, vv.y, o1);
        o2 = fmaf(e2, vv.z, o2);
        o3 = fmaf(e3, vv.w, o3);
    }
    spart[p][r] = (s0 + s1) + (s2 + s3);
    opart[p][r] = (o0 + o1) + (o2 + o3);
    __syncthreads();

    if (tid < ROWS) {
        float s = 0.f, o = 0.f;
#pragma unroll
        for (int pp = 0; pp < NP; ++pp) { s += spart[pp][tid]; o += opart[pp][tid]; }
        const float outv = o / s;
        // y = out*gamma + x  (d==1 broadcasts over C)
        const float og = outv * gamma;
        const int i2 = rowbase + tid;
        const float4* xr = reinterpret_cast<const float4*>(xb + (size_t)i2 * CCH);
        float4 b0 = xr[0];
        float4 b1 = xr[1];
        float* yp = y + ((size_t)b * NPIX + i2) * CCH;
        float4 y0 = { og + b0.x, og + b0.y, og + b0.z, og + b0.w };
        float4 y1 = { og + b1.x, og + b1.y, og + b1.z, og + b1.w };
        *reinterpret_cast<float4*>(yp) = y0;
        *reinterpret_cast<float4*>(yp + 4) = y1;
        qrow[tid] = q2;
        crow[tid] = m2 + log2f(s);
    }
    __syncthreads();

    // ---- stream the attention tile: ROWS x 4096, k cached in registers ----
    // Each thread owns 4 float4 column-groups (16 columns), row-invariant.
    const int j4 = tid * 4;
    float4 kk0 = *reinterpret_cast<const float4*>(&ks[j4]);
    float4 kk1 = *reinterpret_cast<const float4*>(&ks[j4 + BLK * 4]);
    float4 kk2 = *reinterpret_cast<const float4*>(&ks[j4 + BLK * 8]);
    float4 kk3 = *reinterpret_cast<const float4*>(&ks[j4 + BLK * 12]);

    float* ap0 = attn + ((size_t)b * NPIX + rowbase) * (size_t)NPIX;
    for (int rr = 0; rr < ROWS; ++rr) {
        const float qr = qrow[rr];
        const float cr = crow[rr];
        float* ap = ap0 + (size_t)rr * NPIX;
        floatx4 e0, e1, e2, e3;
        e0.x = exp2f(fmaf(qr, kk0.x, -cr)); e0.y = exp2f(fmaf(qr, kk0.y, -cr));
        e0.z = exp2f(fmaf(qr, kk0.z, -cr)); e0.w = exp2f(fmaf(qr, kk0.w, -cr));
        e1.x = exp2f(fmaf(qr, kk1.x, -cr)); e1.y = exp2f(fmaf(qr, kk1.y, -cr));
        e1.z = exp2f(fmaf(qr, kk1.z, -cr)); e1.w = exp2f(fmaf(qr, kk1.w, -cr));
        e2.x = exp2f(fmaf(qr, kk2.x, -cr)); e2.y = exp2f(fmaf(qr, kk2.y, -cr));
        e2.z = exp2f(fmaf(qr, kk2.z, -cr)); e2.w = exp2f(fmaf(qr, kk2.w, -cr));
        e3.x = exp2f(fmaf(qr, kk3.x, -cr)); e3.y = exp2f(fmaf(qr, kk3.y, -cr));
        e3.z = exp2f(fmaf(qr, kk3.z, -cr)); e3.w = exp2f(fmaf(qr, kk3.w, -cr));
        __builtin_nontemporal_store(e0, reinterpret_cast<floatx4*>(&ap[j4]));
        __builtin_nontemporal_store(e1, reinterpret_cast<floatx4*>(&ap[j4 + BLK * 4]));
        __builtin_nontemporal_store(e2, reinterpret_cast<floatx4*>(&ap[j4 + BLK * 8]));
        __builtin_nontemporal_store(e3, reinterpret_cast<floatx4*>(&ap[j4 + BLK * 12]));
    }
}

extern "C" void kernel_launch(void* const* d_in, const int* in_sizes, int n_in,
                              void* d_out, int out_size, void* d_ws, size_t ws_size,
                              hipStream_t stream) {
    const float* x   = (const float*)d_in[0];
    const float* Wq  = (const float*)d_in[1];
    const float* bq  = (const float*)d_in[2];
    const float* Wk  = (const float*)d_in[3];
    const float* bk  = (const float*)d_in[4];
    const float* Wv  = (const float*)d_in[5];
    const float* bv  = (const float*)d_in[6];
    const float* gm  = (const float*)d_in[7];

    const int B = in_sizes[0] / (NPIX * CCH);   // = 8
    float* y    = (float*)d_out;
    float* attn = y + (size_t)B * NPIX * CCH;   // attention follows y, flat

    dim3 grid(NPIX / ROWS, B);
    attn_fused<<<grid, BLK, 0, stream>>>(x, Wq, bq, Wk, bk, Wv, bv, gm, y, attn);
}